// Round 4
// baseline (22370.361 us; speedup 1.0000x reference)
//
#include <hip/hip_runtime.h>

#define S_LEN 512
#define BATCH 128
#define NH    128
#define NL    3

typedef float f32x4 __attribute__((ext_vector_type(4)));
typedef short bf16x8 __attribute__((ext_vector_type(8)));

__device__ __forceinline__ short f2bf(float f) {
    unsigned u = __builtin_bit_cast(unsigned, f);
    u = (u + 0x7FFFu + ((u >> 16) & 1u)) >> 16;
    return (short)u;
}
__device__ __forceinline__ float bf2f(short s) {
    unsigned u = ((unsigned)(unsigned short)s) << 16;
    return __builtin_bit_cast(float, u);
}
__device__ __forceinline__ float sigm(float x) { return 1.f / (1.f + __expf(-x)); }
__device__ __forceinline__ float tanh_fast(float x) { return 2.f / (1.f + __expf(-2.f * x)) - 1.f; }

// ---------------- K1: xp = x @ lin_w.T + lin_b  ->  bf16 [S*B][H] ----------------
__global__ __launch_bounds__(128) void xp_kernel(const float* __restrict__ x,
        const float* __restrict__ lin_w, const float* __restrict__ lin_b,
        short* __restrict__ xp) {
    __shared__ float xs[8 * 128];
    const int tid = threadIdx.x;
    const long r0 = (long)blockIdx.x * 8;
    for (int rr = 0; rr < 8; ++rr)
        xs[rr * 128 + tid] = x[(r0 + rr) * 128 + tid];
    __syncthreads();
    float acc[8];
    float bias = lin_b[tid];
    #pragma unroll
    for (int rr = 0; rr < 8; ++rr) acc[rr] = bias;
    const float* wrow = lin_w + (long)tid * 128;
    for (int k = 0; k < 128; ++k) {
        float wv = wrow[k];
        #pragma unroll
        for (int rr = 0; rr < 8; ++rr) acc[rr] += xs[rr * 128 + k] * wv;
    }
    for (int rr = 0; rr < 8; ++rr)
        xp[(r0 + rr) * 128 + tid] = f2bf(acc[rr]);
}

// ---------------- K2: pack W,U wave-major for the 12-wave main kernel ----------------
// Wave w (l = w>>2, hc = w&3) owns n-tiles: n = g*128 + hc*32 + s*16, g<4 (gate), s<2.
// Fragment: lane(lr=lane&15, lk=lane>>4), elem j -> row n_tile+lr, col kt*32 + lk*8 + j.
// Wp frag id = (w*4 + kt)*8 + (g*2+s)   [384 frags]
// Up frag id = (w*12 + kt)*8 + (g*2+s)  [1152 frags]
__global__ __launch_bounds__(256) void pack_kernel(const float* __restrict__ W,
        const float* __restrict__ U, short* __restrict__ Wp, short* __restrict__ Up) {
    int id = blockIdx.x * 256 + threadIdx.x;     // 98304 = 1536 frags * 64 lanes
    int lane = id & 63;
    int fid = id >> 6;
    int lr = lane & 15, lk = lane >> 4;
    if (fid < 384) {
        int gs = fid & 7, kt = (fid >> 3) & 3, w = fid >> 5;
        int g = gs >> 1, s = gs & 1, l = w >> 2, hc = w & 3;
        int nrow = g * 128 + hc * 32 + s * 16 + lr;
        const float* src = W + ((long)(l * 512 + nrow)) * 128 + kt * 32 + lk * 8;
        short* dst = Wp + (long)fid * 512 + lane * 8;
        #pragma unroll
        for (int j = 0; j < 8; ++j) dst[j] = f2bf(src[j]);
    } else {
        int f = fid - 384;
        int gs = f & 7, m = f >> 3;
        int kt = m % 12, w = m / 12;
        int g = gs >> 1, s = gs & 1, l = w >> 2, hc = w & 3;
        int nrow = g * 128 + hc * 32 + s * 16 + lr;
        const float* src = U + ((long)(l * 512 + nrow)) * 384 + kt * 32 + lk * 8;
        short* dst = Up + (long)f * 512 + lane * 8;
        #pragma unroll
        for (int j = 0; j < 8; ++j) dst[j] = f2bf(src[j]);
    }
}

// ---------------- main persistent recurrence: 8 wgs x 16 batch rows, 12 waves ----------------
#define HLS 132   // h row stride (shorts): 128 + 4
#define HXS 392   // hx row stride (shorts)

__global__ __launch_bounds__(768, 3) void lstm_kernel(
    const short* __restrict__ xp, const short* __restrict__ Wp,
    const short* __restrict__ Up, const float* __restrict__ Gp,
    float* __restrict__ out)
{
    __shared__ short h_lds[NL * 16 * HLS];   // 12672 B
    __shared__ short hx_lds[16 * HXS];       // 12544 B
    __shared__ float G_lds[NL * 128];        //  1536 B

    const int tid = threadIdx.x;
    const int lane = tid & 63;
    const int w = tid >> 6;          // wave 0..11
    const int lr = lane & 15;
    const int lk = lane >> 4;
    const int b0 = blockIdx.x * 16;
    const int lw = w >> 2;           // owned layer 0..2
    const int hc = w & 3;            // owned 32-col h-chunk

    for (int i = tid; i < NL * 16 * HLS; i += 768) h_lds[i] = 0;
    if (tid < NL * 128) G_lds[tid] = Gp[tid];
    float c_reg[2][4];
    #pragma unroll
    for (int s = 0; s < 2; ++s) { c_reg[s][0] = c_reg[s][1] = c_reg[s][2] = c_reg[s][3] = 0.f; }
    __syncthreads();

    const short* UW = Up + (long)w * 96 * 512 + lane * 8;   // 96 frags/wave
    const short* WW = Wp + (long)w * 32 * 512 + lane * 8;   // 32 frags/wave

    for (int t = 0; t < S_LEN; ++t) {
        const short* xp_t = xp + ((long)t * BATCH + b0) * 128;
        bf16x8 xa[4];
        bf16x8 wb[2][8];

        if (lw == 0) {   // layer-0 waves: prefetch xp A-frags + W kt0 group early
            #pragma unroll
            for (int kt = 0; kt < 4; ++kt)
                xa[kt] = *(const bf16x8*)(xp_t + lr * 128 + kt * 32 + lk * 8);
            #pragma unroll
            for (int i = 0; i < 8; ++i)
                wb[0][i] = *(const bf16x8*)(WW + i * 512);
        }

        // ---- phase 0: per-(l,b) scalar gate, build hx (gated h, bf16) ----
        #pragma unroll
        for (int i = 0; i < 4; ++i) {
            int d = w * 4 + i;           // 48 (l,b) dots over 12 waves
            int l = d >> 4, b = d & 15;
            float h0 = bf2f(h_lds[(l * 16 + b) * HLS + 2 * lane]);
            float h1 = bf2f(h_lds[(l * 16 + b) * HLS + 2 * lane + 1]);
            float p = h0 * G_lds[l * 128 + 2 * lane] + h1 * G_lds[l * 128 + 2 * lane + 1];
            #pragma unroll
            for (int m = 32; m >= 1; m >>= 1) p += __shfl_xor(p, m, 64);
            float gh = sigm(p);
            hx_lds[b * HXS + l * 128 + 2 * lane]     = f2bf(gh * h0);
            hx_lds[b * HXS + l * 128 + 2 * lane + 1] = f2bf(gh * h1);
        }
        __syncthreads();   // b1: hx ready

        // ---- U phase: all waves, register-double-buffered weight stream ----
        f32x4 acc[4][2];
        #pragma unroll
        for (int g = 0; g < 4; ++g)
            #pragma unroll
            for (int s = 0; s < 2; ++s)
                acc[g][s] = (f32x4){0.f, 0.f, 0.f, 0.f};

        bf16x8 ub[2][8];
        #pragma unroll
        for (int i = 0; i < 8; ++i) ub[0][i] = *(const bf16x8*)(UW + i * 512);

        #pragma unroll
        for (int kt = 0; kt < 12; ++kt) {
            if (kt < 11) {
                #pragma unroll
                for (int i = 0; i < 8; ++i)
                    ub[(kt + 1) & 1][i] = *(const bf16x8*)(UW + ((kt + 1) * 8 + i) * 512);
            }
            bf16x8 a = *(const bf16x8*)&hx_lds[lr * HXS + kt * 32 + lk * 8];
            #pragma unroll
            for (int gs = 0; gs < 8; ++gs)
                acc[gs >> 1][gs & 1] =
                    __builtin_amdgcn_mfma_f32_16x16x32_bf16(a, ub[kt & 1][gs], acc[gs >> 1][gs & 1], 0, 0, 0);
        }

        if (lw != 0) {   // preload own W kt0 group while waiting for the chain
            #pragma unroll
            for (int i = 0; i < 8; ++i)
                wb[0][i] = *(const bf16x8*)(WW + i * 512);
        }

        // ---- serial layer chain: W-GEMM + in-register cell ----
        #pragma unroll 1
        for (int lc = 0; lc < NL; ++lc) {
            if (lw == lc) {
                #pragma unroll
                for (int kt = 0; kt < 4; ++kt) {
                    if (kt < 3) {
                        #pragma unroll
                        for (int i = 0; i < 8; ++i)
                            wb[(kt + 1) & 1][i] = *(const bf16x8*)(WW + ((kt + 1) * 8 + i) * 512);
                    }
                    bf16x8 a;
                    if (lc == 0) a = xa[kt];
                    else a = *(const bf16x8*)&h_lds[((lc - 1) * 16 + lr) * HLS + kt * 32 + lk * 8];
                    #pragma unroll
                    for (int gs = 0; gs < 8; ++gs)
                        acc[gs >> 1][gs & 1] =
                            __builtin_amdgcn_mfma_f32_16x16x32_bf16(a, wb[kt & 1][gs], acc[gs >> 1][gs & 1], 0, 0, 0);
                }
                #pragma unroll
                for (int s = 0; s < 2; ++s)
                    #pragma unroll
                    for (int r = 0; r < 4; ++r) {
                        float ig = sigm(acc[0][s][r]);
                        float fg = sigm(acc[1][s][r]);
                        float gg = tanh_fast(acc[2][s][r]);
                        float og = sigm(acc[3][s][r]);
                        float cn = fg * c_reg[s][r] + ig * gg;
                        c_reg[s][r] = cn;
                        float hy = og * tanh_fast(cn);
                        h_lds[(lw * 16 + lk * 4 + r) * HLS + hc * 32 + s * 16 + lr] = f2bf(hy);
                        if (t == S_LEN - 1) {
                            long o = ((long)(lw * BATCH + b0 + lk * 4 + r)) * 128 + hc * 32 + s * 16 + lr;
                            out[o] = hy;
                            out[(long)NL * BATCH * NH + o] = cn;
                        }
                    }
            }
            __syncthreads();   // b2/b3/b4: layer lc's h ready
        }
    }
}

extern "C" void kernel_launch(void* const* d_in, const int* in_sizes, int n_in,
                              void* d_out, int out_size, void* d_ws, size_t ws_size,
                              hipStream_t stream) {
    const float* x     = (const float*)d_in[0];
    const float* lin_w = (const float*)d_in[1];
    const float* lin_b = (const float*)d_in[2];
    const float* W     = (const float*)d_in[3];
    const float* U     = (const float*)d_in[4];
    const float* G     = (const float*)d_in[5];
    float* out = (float*)d_out;

    short* xp = (short*)d_ws;
    short* Wp = (short*)((char*)d_ws + 16777216);
    short* Up = (short*)((char*)d_ws + 16777216 + 393216);

    hipLaunchKernelGGL(xp_kernel,   dim3(8192), dim3(128), 0, stream, x, lin_w, lin_b, xp);
    hipLaunchKernelGGL(pack_kernel, dim3(384),  dim3(256), 0, stream, W, U, Wp, Up);
    hipLaunchKernelGGL(lstm_kernel, dim3(8),    dim3(768), 0, stream, xp, Wp, Up, G, out);
}